// Round 3
// baseline (109.911 us; speedup 1.0000x reference)
//
#include <hip/hip_runtime.h>
#include <stdint.h>

// Problem constants (fixed by setup_inputs)
#define NB 32
#define NC 128
#define NH 56
#define NW 56
#define NHW_ (NH * NW)      // 3136
#define NPIX (NB * NHW_)    // 100352
#define NO 128
#define NK 1152             // NC * 9
#define NSTRIP 14           // NH / 4

typedef unsigned long long u64;

// ---------------------------------------------------------------------------
// K1: sign(x + bias0) packed into 128-bit-per-pixel bitplanes.
// ---------------------------------------------------------------------------
__global__ __launch_bounds__(256) void pack_act(const float* __restrict__ x,
                                                const float* __restrict__ bias0,
                                                u64* __restrict__ packA) {
    int p = blockIdx.x * 256 + threadIdx.x;  // pixel index n*HW + h*W + w
    if (p >= NPIX) return;
    int n = p / NHW_;
    int rem = p - n * NHW_;
    const float* xb = x + (size_t)n * NC * NHW_ + rem;
    u64 w0 = 0, w1 = 0;
#pragma unroll 8
    for (int c = 0; c < 64; ++c)
        w0 |= (u64)((xb[(size_t)c * NHW_] + bias0[c]) > 0.f) << c;
#pragma unroll 8
    for (int c = 0; c < 64; ++c)
        w1 |= (u64)((xb[(size_t)(c + 64) * NHW_] + bias0[c + 64]) > 0.f) << c;
    packA[(size_t)p * 2]     = w0;
    packA[(size_t)p * 2 + 1] = w1;
}

// ---------------------------------------------------------------------------
// K2: per-output-channel weight scale (mean |w|) + sign bitplanes + border
// correction table. corrW[o][0..7] = {sumL,sumR,sumT,sumB,c0,c2,c6,c8} where
// cv[t] = 128 - 2*popc(wbits[t]) is the dot contribution of a zeroed tap.
// ---------------------------------------------------------------------------
__global__ __launch_bounds__(64) void pack_wgt(const float* __restrict__ w,
                                               u64* __restrict__ packW,
                                               float* __restrict__ scaleW,
                                               int* __restrict__ corrW) {
    __shared__ u64 sb[18];
    int o = blockIdx.x;
    int t = threadIdx.x;  // 64 threads
    const float* wo = w + (size_t)o * NK;
    float s = 0.f;
    for (int i = t; i < NK; i += 64) s += fabsf(wo[i]);
    for (int off = 32; off; off >>= 1) s += __shfl_down(s, off);
    if (t == 0) scaleW[o] = s / (float)NK;
    if (t < 18) {
        int tap = t >> 1;
        int j   = t & 1;
        u64 bits = 0;
        for (int cc = 0; cc < 64; ++cc) {
            int c = j * 64 + cc;
            bits |= (u64)(wo[c * 9 + tap] > 0.f) << cc;
        }
        packW[(size_t)o * 18 + t] = bits;
        sb[t] = bits;
    }
    __syncthreads();
    if (t == 0) {
        int cv[9];
#pragma unroll
        for (int tap = 0; tap < 9; ++tap)
            cv[tap] = NC - 2 * (__popcll(sb[2 * tap]) + __popcll(sb[2 * tap + 1]));
        int* cw = corrW + o * 8;
        cw[0] = cv[0] + cv[3] + cv[6];  // sumL (kw=0 col)
        cw[1] = cv[2] + cv[5] + cv[8];  // sumR (kw=2 col)
        cw[2] = cv[0] + cv[1] + cv[2];  // sumT (kh=0 row)
        cw[3] = cv[6] + cv[7] + cv[8];  // sumB (kh=2 row)
        cw[4] = cv[0];                  // corner overlaps
        cw[5] = cv[2];
        cw[6] = cv[6];
        cw[7] = cv[8];
    }
}

// ---------------------------------------------------------------------------
// K3: binary conv, 4 output rows x 64 channels per block. Unconditional
// xor+popcount chains; border handled by per-channel correction subtract.
// Grid: n(32) x strip(14) x chhalf(2) = 896 blocks; 4 waves x 16 channels.
// ---------------------------------------------------------------------------
__global__ __launch_bounds__(256, 4) void conv_bin(const u64* __restrict__ packA,
                                                   const u64* __restrict__ packW,
                                                   const int* __restrict__ corrW,
                                                   short* __restrict__ yI) {
    __shared__ u64 lw[64 * 18];  // 9216 B
    __shared__ int lc[64 * 8];   // 2048 B

    int bid = blockIdx.x;
    int n = bid / (NSTRIP * 2);
    int rem = bid - n * (NSTRIP * 2);
    int strip = rem >> 1;
    int chh = rem & 1;
    int obase = chh * 64;
    int h0 = strip * 4;

    for (int i = threadIdx.x; i < 64 * 18; i += 256) lw[i] = packW[(size_t)obase * 18 + i];
    for (int i = threadIdx.x; i < 64 * 8; i += 256) lc[i] = corrW[obase * 8 + i];

    int wv = threadIdx.x >> 6, lane = threadIdx.x & 63;
    bool act = lane < NW;
    bool top = (strip == 0), bot = (strip == NSTRIP - 1);

    // 6 input rows (h0-1..h0+4) x 3 cols x 2 words = 72 VGPRs
    u64 a[6][3][2];
    bool cvv[3];
    cvv[0] = act && (lane >= 1);
    cvv[1] = act;
    cvv[2] = act && (lane + 1 < NW);
#pragma unroll
    for (int r = 0; r < 6; ++r) {
        int hi = h0 - 1 + r;
        bool rvv = (hi >= 0) && (hi < NH);
        int hc = hi < 0 ? 0 : (hi >= NH ? NH - 1 : hi);
#pragma unroll
        for (int c = 0; c < 3; ++c) {
            int wi = lane - 1 + c;
            int wc = wi < 0 ? 0 : (wi >= NW ? NW - 1 : wi);
            ulonglong2 q = *reinterpret_cast<const ulonglong2*>(
                packA + ((size_t)n * NHW_ + (size_t)hc * NW + wc) * 2);
            bool v = rvv && cvv[c];
            a[r][c][0] = v ? q.x : 0;
            a[r][c][1] = v ? q.y : 0;
        }
    }
    __syncthreads();

    bool isL = (lane == 0), isR = (lane == NW - 1);
    short* ybase = yI + (size_t)n * NO * NHW_ + (size_t)h0 * NW + lane;

    for (int oo = 0; oo < 16; ++oo) {
        int lo = (wv << 4) + oo;       // local channel 0..63
        int o = obase + lo;            // global channel
        const u64* wp = &lw[lo * 18];
        int pc0 = 0, pc1 = 0, pc2 = 0, pc3 = 0;
#pragma unroll
        for (int kh = 0; kh < 3; ++kh) {
#pragma unroll
            for (int kw = 0; kw < 3; ++kw) {
                u64 w0 = wp[(kh * 3 + kw) * 2];
                u64 w1 = wp[(kh * 3 + kw) * 2 + 1];
                pc0 += __popcll(a[0 + kh][kw][0] ^ w0) + __popcll(a[0 + kh][kw][1] ^ w1);
                pc1 += __popcll(a[1 + kh][kw][0] ^ w0) + __popcll(a[1 + kh][kw][1] ^ w1);
                pc2 += __popcll(a[2 + kh][kw][0] ^ w0) + __popcll(a[2 + kh][kw][1] ^ w1);
                pc3 += __popcll(a[3 + kh][kw][0] ^ w0) + __popcll(a[3 + kh][kw][1] ^ w1);
            }
        }
        const int* cw = &lc[lo * 8];
        int corrcol = isL ? cw[0] : (isR ? cw[1] : 0);
        int base = NK - corrcol;
        int d0 = base - 2 * pc0;
        int d1 = base - 2 * pc1;
        int d2 = base - 2 * pc2;
        int d3 = base - 2 * pc3;
        if (top) d0 -= cw[2] - (isL ? cw[4] : (isR ? cw[5] : 0));
        if (bot) d3 -= cw[3] - (isL ? cw[6] : (isR ? cw[7] : 0));
        if (act) {
            short* yp = ybase + (size_t)o * NHW_;
            yp[0]      = (short)d0;
            yp[NW]     = (short)d1;
            yp[2 * NW] = (short)d2;
            yp[3 * NW] = (short)d3;
        }
    }
}

// ---------------------------------------------------------------------------
// K4: per-channel stats + BN coefficient fold. One block per channel; exact
// integer sums; thread 0 writes coefA/coefB. No atomics, no extra launch.
// ---------------------------------------------------------------------------
__global__ __launch_bounds__(256) void stats_coef(const short* __restrict__ yI,
                                                  const float* __restrict__ scaleW,
                                                  const float* __restrict__ gamma,
                                                  const float* __restrict__ beta,
                                                  const float* __restrict__ bias1,
                                                  float* __restrict__ coefA,
                                                  float* __restrict__ coefB) {
    int o = blockIdx.x;
    long long s = 0, sq = 0;
    // 32 planes x 392 int4(=8 shorts) vectors = 12544 vectors
    for (int v = threadIdx.x; v < 12544; v += 256) {
        int n = v / 392, off = v - n * 392;
        const int4 pv = *reinterpret_cast<const int4*>(
            yI + ((size_t)n * NO + o) * NHW_ + (size_t)off * 8);
        int qs[4] = {pv.x, pv.y, pv.z, pv.w};
#pragma unroll
        for (int j = 0; j < 4; ++j) {
            int lo = (int)(short)(qs[j] & 0xffff);
            int hi = (int)(qs[j] >> 16);
            s += lo + hi;
            sq += (long long)(lo * lo + hi * hi);
        }
    }
    __shared__ long long ls[256];
    __shared__ long long lq[256];
    int tid = threadIdx.x;
    ls[tid] = s; lq[tid] = sq;
    __syncthreads();
    for (int st = 128; st; st >>= 1) {
        if (tid < st) { ls[tid] += ls[tid + st]; lq[tid] += lq[tid + st]; }
        __syncthreads();
    }
    if (tid == 0) {
        double cnt = (double)NPIX;
        double mean = (double)ls[0] / cnt;
        double var = (double)lq[0] / cnt - mean * mean;
        if (var < 0.0) var = 0.0;
        float sc = scaleW[o];
        float rs = rsqrtf((float)((double)sc * (double)sc * var) + 1e-5f);
        float g = gamma[o];
        coefA[o] = sc * g * rs;
        coefB[o] = beta[o] - (float)((double)sc * mean) * g * rs + bias1[o];
    }
}

// ---------------------------------------------------------------------------
// K5: elementwise epilogue, 8 elems/thread vectorized.
// out = prelu(coefA*y + coefB + x) + bias2
// ---------------------------------------------------------------------------
__global__ __launch_bounds__(256) void final_store(const short* __restrict__ yI,
                                                   const float* __restrict__ x,
                                                   const float* __restrict__ coefA,
                                                   const float* __restrict__ coefB,
                                                   const float* __restrict__ alpha,
                                                   const float* __restrict__ bias2,
                                                   float* __restrict__ out) {
    const size_t ngroups = (size_t)NB * NO * NHW_ / 8;
    for (size_t g = (size_t)blockIdx.x * blockDim.x + threadIdx.x; g < ngroups;
         g += (size_t)gridDim.x * blockDim.x) {
        size_t i = g * 8;
        int o = (int)((i / NHW_) % NO);
        float a = coefA[o], bb = coefB[o], al = alpha[o], b2 = bias2[o];
        int4 yv = *reinterpret_cast<const int4*>(yI + i);
        float4 x0 = *reinterpret_cast<const float4*>(x + i);
        float4 x1 = *reinterpret_cast<const float4*>(x + i + 4);
        int q[4] = {yv.x, yv.y, yv.z, yv.w};
        float xs[8] = {x0.x, x0.y, x0.z, x0.w, x1.x, x1.y, x1.z, x1.w};
        float r[8];
#pragma unroll
        for (int j = 0; j < 4; ++j) {
            float lo = (float)(short)(q[j] & 0xffff);
            float hi = (float)(q[j] >> 16);
            float t0 = fmaf(a, lo, bb) + xs[2 * j];
            float t1 = fmaf(a, hi, bb) + xs[2 * j + 1];
            t0 = t0 >= 0.f ? t0 : al * t0;
            t1 = t1 >= 0.f ? t1 : al * t1;
            r[2 * j]     = t0 + b2;
            r[2 * j + 1] = t1 + b2;
        }
        float4 o0 = {r[0], r[1], r[2], r[3]};
        float4 o1 = {r[4], r[5], r[6], r[7]};
        *reinterpret_cast<float4*>(out + i)     = o0;
        *reinterpret_cast<float4*>(out + i + 4) = o1;
    }
}

// ---------------------------------------------------------------------------
// Fallback path (tiny-ws): atomic-based stats conv + recompute epilogue.
// ---------------------------------------------------------------------------
__device__ inline void load_nbhd(const u64* __restrict__ packA, int n, int h,
                                 int wcol, bool act, u64 a[9][2], unsigned* vmask) {
    unsigned m = 0;
#pragma unroll
    for (int kh = 0; kh < 3; ++kh) {
        int hi = h + kh - 1;
        bool vh = (hi >= 0) && (hi < NH);
#pragma unroll
        for (int kw = 0; kw < 3; ++kw) {
            int wi = wcol + kw - 1;
            int t = kh * 3 + kw;
            bool v = act && vh && (wi >= 0) && (wi < NW);
            int hc = hi < 0 ? 0 : (hi >= NH ? NH - 1 : hi);
            int wc = wi < 0 ? 0 : (wi >= NW ? NW - 1 : wi);
            size_t idx = ((size_t)n * NHW_ + (size_t)hc * NW + wc) * 2;
            u64 q0 = packA[idx], q1 = packA[idx + 1];
            a[t][0] = v ? q0 : 0;
            a[t][1] = v ? q1 : 0;
            m |= (unsigned)v << t;
        }
    }
    *vmask = m;
}

__global__ __launch_bounds__(256) void conv_stats_atomic(const u64* __restrict__ packA,
                                                         const u64* __restrict__ packW,
                                                         int* __restrict__ sumI,
                                                         u64* __restrict__ sumsqI) {
    __shared__ u64 lw[NO * 18];
    for (int i = threadIdx.x; i < NO * 18; i += 256) lw[i] = packW[i];
    int nh = blockIdx.x;
    int n = nh / NH, h = nh - n * NH;
    int wave = threadIdx.x >> 6, lane = threadIdx.x & 63;
    bool act = lane < NW;
    u64 a[9][2]; unsigned vm;
    load_nbhd(packA, n, h, lane, act, a, &vm);
    __syncthreads();
    for (int oo = 0; oo < 32; ++oo) {
        int o = (wave << 5) + oo;
        int dot = 0;
#pragma unroll
        for (int t = 0; t < 9; ++t) {
            int pc = __popcll(a[t][0] ^ lw[(o * 9 + t) * 2]) +
                     __popcll(a[t][1] ^ lw[(o * 9 + t) * 2 + 1]);
            dot += ((vm >> t) & 1) ? (NC - 2 * pc) : 0;
        }
        int s = dot, sq = dot * dot;
        for (int off = 32; off; off >>= 1) {
            s  += __shfl_down(s, off);
            sq += __shfl_down(sq, off);
        }
        if (lane == 0) {
            atomicAdd(&sumI[o], s);
            atomicAdd(&sumsqI[o], (u64)(unsigned)sq);
        }
    }
}

__global__ __launch_bounds__(128) void bn_coef(const int* __restrict__ sumP,
                                               const u64* __restrict__ sqP,
                                               const float* __restrict__ scaleW,
                                               const float* __restrict__ gamma,
                                               const float* __restrict__ beta,
                                               const float* __restrict__ bias1,
                                               float* __restrict__ coefA,
                                               float* __restrict__ coefB) {
    int o = threadIdx.x;
    double cnt = (double)NPIX;
    double mean = (double)sumP[o] / cnt;
    double var = (double)sqP[o] / cnt - mean * mean;
    if (var < 0.0) var = 0.0;
    float sc = scaleW[o];
    float rs = rsqrtf((float)((double)sc * (double)sc * var) + 1e-5f);
    float g = gamma[o];
    coefA[o] = sc * g * rs;
    coefB[o] = beta[o] - (float)((double)sc * mean) * g * rs + bias1[o];
}

__global__ __launch_bounds__(256) void final_recompute(const u64* __restrict__ packA,
                                                       const u64* __restrict__ packW,
                                                       const float* __restrict__ coefA,
                                                       const float* __restrict__ coefB,
                                                       const float* __restrict__ alpha,
                                                       const float* __restrict__ bias2,
                                                       const float* __restrict__ x,
                                                       float* __restrict__ out) {
    __shared__ u64 lw[NO * 18];
    for (int i = threadIdx.x; i < NO * 18; i += 256) lw[i] = packW[i];
    int nh = blockIdx.x;
    int n = nh / NH, h = nh - n * NH;
    int wave = threadIdx.x >> 6, lane = threadIdx.x & 63;
    bool act = lane < NW;
    u64 a[9][2]; unsigned vm;
    load_nbhd(packA, n, h, lane, act, a, &vm);
    __syncthreads();
    for (int oo = 0; oo < 32; ++oo) {
        int o = (wave << 5) + oo;
        int dot = 0;
#pragma unroll
        for (int t = 0; t < 9; ++t) {
            int pc = __popcll(a[t][0] ^ lw[(o * 9 + t) * 2]) +
                     __popcll(a[t][1] ^ lw[(o * 9 + t) * 2 + 1]);
            dot += ((vm >> t) & 1) ? (NC - 2 * pc) : 0;
        }
        if (act) {
            size_t idx = ((size_t)n * NO + o) * NHW_ + (size_t)h * NW + lane;
            float t = fmaf(coefA[o], (float)dot, coefB[o]) + x[idx];
            t = t >= 0.f ? t : alpha[o] * t;
            out[idx] = t + bias2[o];
        }
    }
}

// ---------------------------------------------------------------------------
// Workspace layout (bytes):
//   0        packA   (NB*HW*2 u64)      1,605,632
//   1605632  packW   (128*18 u64)          18,432
//   1624064  corrW   (128*8 i32)            4,096
//   1628160  scaleW  (128 f32)                512
//   1628672  coefA   (128 f32)                512
//   1629184  coefB   (128 f32)                512
//   1629696  sumP    (128 i32, fallback)      512
//   1630208  sqP     (128 u64, fallback)    1,024
//   1631232  yI      (int16)           25,690,112   (store path)
// ---------------------------------------------------------------------------
extern "C" void kernel_launch(void* const* d_in, const int* in_sizes, int n_in,
                              void* d_out, int out_size, void* d_ws, size_t ws_size,
                              hipStream_t stream) {
    (void)in_sizes; (void)n_in; (void)out_size;
    const float* x     = (const float*)d_in[0];
    const float* bias0 = (const float*)d_in[1];
    const float* w     = (const float*)d_in[2];
    const float* gamma = (const float*)d_in[3];
    const float* beta  = (const float*)d_in[4];
    const float* bias1 = (const float*)d_in[5];
    const float* alpha = (const float*)d_in[6];
    const float* bias2 = (const float*)d_in[7];
    float* out = (float*)d_out;
    char* ws = (char*)d_ws;

    u64*   packA  = (u64*)ws;
    u64*   packW  = (u64*)(ws + 1605632);
    int*   corrW  = (int*)(ws + 1624064);
    float* scaleW = (float*)(ws + 1628160);
    float* coefA  = (float*)(ws + 1628672);
    float* coefB  = (float*)(ws + 1629184);
    int*   sumP   = (int*)(ws + 1629696);
    u64*   sqP    = (u64*)(ws + 1630208);
    short* yI     = (short*)(ws + 1631232);
    bool store = ws_size >= (size_t)1631232 + (size_t)NB * NO * NHW_ * 2;

    pack_act<<<NPIX / 256, 256, 0, stream>>>(x, bias0, packA);
    pack_wgt<<<NO, 64, 0, stream>>>(w, packW, scaleW, corrW);

    if (store) {
        conv_bin<<<NB * NSTRIP * 2, 256, 0, stream>>>(packA, packW, corrW, yI);
        stats_coef<<<NO, 256, 0, stream>>>(yI, scaleW, gamma, beta, bias1, coefA, coefB);
        final_store<<<2048, 256, 0, stream>>>(yI, x, coefA, coefB, alpha, bias2, out);
    } else {
        hipMemsetAsync(sumP, 0, 512 + 1024, stream);
        conv_stats_atomic<<<NB * NH, 256, 0, stream>>>(packA, packW, sumP, sqP);
        bn_coef<<<1, NO, 0, stream>>>(sumP, sqP, scaleW, gamma, beta, bias1, coefA, coefB);
        final_recompute<<<NB * NH, 256, 0, stream>>>(packA, packW, coefA, coefB, alpha, bias2, x, out);
    }
}

// Round 4
// 93.338 us; speedup vs baseline: 1.1776x; 1.1776x over previous
//
#include <hip/hip_runtime.h>
#include <stdint.h>

// Problem constants (fixed by setup_inputs)
#define NB 32
#define NC 128
#define NH 56
#define NW 56
#define NHW_ (NH * NW)      // 3136
#define NPIX (NB * NHW_)    // 100352
#define NO 128
#define NK 1152             // NC * 9
#define NSTRIP 14           // NH / 4
#define NSLOT (NB * NSTRIP) // 448 partial slots per channel

typedef unsigned long long u64;

// ---------------------------------------------------------------------------
// K1: sign(x + bias0) packed into 128-bit-per-pixel bitplanes.
// ---------------------------------------------------------------------------
__global__ __launch_bounds__(256) void pack_act(const float* __restrict__ x,
                                                const float* __restrict__ bias0,
                                                u64* __restrict__ packA) {
    int p = blockIdx.x * 256 + threadIdx.x;  // pixel index n*HW + h*W + w
    if (p >= NPIX) return;
    int n = p / NHW_;
    int rem = p - n * NHW_;
    const float* xb = x + (size_t)n * NC * NHW_ + rem;
    u64 w0 = 0, w1 = 0;
#pragma unroll 8
    for (int c = 0; c < 64; ++c)
        w0 |= (u64)((xb[(size_t)c * NHW_] + bias0[c]) > 0.f) << c;
#pragma unroll 8
    for (int c = 0; c < 64; ++c)
        w1 |= (u64)((xb[(size_t)(c + 64) * NHW_] + bias0[c + 64]) > 0.f) << c;
    packA[(size_t)p * 2]     = w0;
    packA[(size_t)p * 2 + 1] = w1;
}

// ---------------------------------------------------------------------------
// K2: per-output-channel weight scale (mean |w|) + sign bitplanes + border
// correction table. corrW[o][0..7] = {sumL,sumR,sumT,sumB,c0,c2,c6,c8} where
// cv[t] = 128 - 2*popc(wbits[t]) is the dot contribution of a zeroed tap.
// ---------------------------------------------------------------------------
__global__ __launch_bounds__(64) void pack_wgt(const float* __restrict__ w,
                                               u64* __restrict__ packW,
                                               float* __restrict__ scaleW,
                                               int* __restrict__ corrW) {
    __shared__ u64 sb[18];
    int o = blockIdx.x;
    int t = threadIdx.x;  // 64 threads
    const float* wo = w + (size_t)o * NK;
    float s = 0.f;
    for (int i = t; i < NK; i += 64) s += fabsf(wo[i]);
    for (int off = 32; off; off >>= 1) s += __shfl_down(s, off);
    if (t == 0) scaleW[o] = s / (float)NK;
    if (t < 18) {
        int tap = t >> 1;
        int j   = t & 1;
        u64 bits = 0;
        for (int cc = 0; cc < 64; ++cc) {
            int c = j * 64 + cc;
            bits |= (u64)(wo[c * 9 + tap] > 0.f) << cc;
        }
        packW[(size_t)o * 18 + t] = bits;
        sb[t] = bits;
    }
    __syncthreads();
    if (t == 0) {
        int cv[9];
#pragma unroll
        for (int tap = 0; tap < 9; ++tap)
            cv[tap] = NC - 2 * (__popcll(sb[2 * tap]) + __popcll(sb[2 * tap + 1]));
        int* cw = corrW + o * 8;
        cw[0] = cv[0] + cv[3] + cv[6];  // sumL (kw=0 col)
        cw[1] = cv[2] + cv[5] + cv[8];  // sumR (kw=2 col)
        cw[2] = cv[0] + cv[1] + cv[2];  // sumT (kh=0 row)
        cw[3] = cv[6] + cv[7] + cv[8];  // sumB (kh=2 row)
        cw[4] = cv[0];                  // corner overlaps
        cw[5] = cv[2];
        cw[6] = cv[6];
        cw[7] = cv[8];
    }
}

// ---------------------------------------------------------------------------
// K3: binary conv, 4 output rows x 32 channels per block, fused BN partial
// stats (wave shuffle reduce, no atomics). Unconditional xor+popcount chains;
// border handled by per-channel correction subtract.
// Grid: n(32) x strip(14) x chgroup(4) = 1792 blocks; 4 waves x 8 channels.
// ---------------------------------------------------------------------------
__global__ __launch_bounds__(256, 3) void conv_bin(const u64* __restrict__ packA,
                                                   const u64* __restrict__ packW,
                                                   const int* __restrict__ corrW,
                                                   short* __restrict__ yI,
                                                   int* __restrict__ sumP,
                                                   int* __restrict__ sqP) {
    __shared__ u64 lw[32 * 18];  // 4608 B
    __shared__ int lc[32 * 8];   // 1024 B

    int bid = blockIdx.x;
    int n = bid / (NSTRIP * 4);
    int rem = bid - n * (NSTRIP * 4);
    int strip = rem >> 2;
    int cg = rem & 3;
    int obase = cg * 32;
    int h0 = strip * 4;

    for (int i = threadIdx.x; i < 32 * 18; i += 256) lw[i] = packW[(size_t)obase * 18 + i];
    if (threadIdx.x < 32 * 8) lc[threadIdx.x] = corrW[obase * 8 + threadIdx.x];

    int wv = threadIdx.x >> 6, lane = threadIdx.x & 63;
    bool act = lane < NW;
    bool top = (strip == 0), bot = (strip == NSTRIP - 1);

    // 6 input rows (h0-1..h0+4) x 3 cols x 2 words = 72 VGPRs
    u64 a[6][3][2];
    bool cvv[3];
    cvv[0] = act && (lane >= 1);
    cvv[1] = act;
    cvv[2] = act && (lane + 1 < NW);
#pragma unroll
    for (int r = 0; r < 6; ++r) {
        int hi = h0 - 1 + r;
        bool rvv = (hi >= 0) && (hi < NH);
        int hc = hi < 0 ? 0 : (hi >= NH ? NH - 1 : hi);
#pragma unroll
        for (int c = 0; c < 3; ++c) {
            int wi = lane - 1 + c;
            int wc = wi < 0 ? 0 : (wi >= NW ? NW - 1 : wi);
            ulonglong2 q = *reinterpret_cast<const ulonglong2*>(
                packA + ((size_t)n * NHW_ + (size_t)hc * NW + wc) * 2);
            bool v = rvv && cvv[c];
            a[r][c][0] = v ? q.x : 0;
            a[r][c][1] = v ? q.y : 0;
        }
    }
    __syncthreads();

    bool isL = (lane == 0), isR = (lane == NW - 1);
    short* ybase = yI + (size_t)n * NO * NHW_ + (size_t)h0 * NW + lane;
    int sl = n * NSTRIP + strip;

    for (int oo = 0; oo < 8; ++oo) {
        int lo = (wv << 3) + oo;       // local channel 0..31
        int o = obase + lo;            // global channel
        const u64* wp = &lw[lo * 18];
        int pc0 = 0, pc1 = 0, pc2 = 0, pc3 = 0;
#pragma unroll
        for (int kh = 0; kh < 3; ++kh) {
#pragma unroll
            for (int kw = 0; kw < 3; ++kw) {
                u64 w0 = wp[(kh * 3 + kw) * 2];
                u64 w1 = wp[(kh * 3 + kw) * 2 + 1];
                pc0 += __popcll(a[0 + kh][kw][0] ^ w0) + __popcll(a[0 + kh][kw][1] ^ w1);
                pc1 += __popcll(a[1 + kh][kw][0] ^ w0) + __popcll(a[1 + kh][kw][1] ^ w1);
                pc2 += __popcll(a[2 + kh][kw][0] ^ w0) + __popcll(a[2 + kh][kw][1] ^ w1);
                pc3 += __popcll(a[3 + kh][kw][0] ^ w0) + __popcll(a[3 + kh][kw][1] ^ w1);
            }
        }
        const int* cw = &lc[lo * 8];
        int corrcol = isL ? cw[0] : (isR ? cw[1] : 0);
        int base = NK - corrcol;
        int d0 = base - 2 * pc0;
        int d1 = base - 2 * pc1;
        int d2 = base - 2 * pc2;
        int d3 = base - 2 * pc3;
        if (top) d0 -= cw[2] - (isL ? cw[4] : (isR ? cw[5] : 0));
        if (bot) d3 -= cw[3] - (isL ? cw[6] : (isR ? cw[7] : 0));
        if (act) {
            short* yp = ybase + (size_t)o * NHW_;
            yp[0]      = (short)d0;
            yp[NW]     = (short)d1;
            yp[2 * NW] = (short)d2;
            yp[3 * NW] = (short)d3;
        }
        // fused BN partial stats: exact integer sums over this block's pixels
        int s = act ? (d0 + d1 + d2 + d3) : 0;
        int q = act ? (d0 * d0 + d1 * d1 + d2 * d2 + d3 * d3) : 0;
#pragma unroll
        for (int off = 32; off; off >>= 1) {
            s += __shfl_down(s, off);
            q += __shfl_down(q, off);
        }
        if (lane == 0) {
            sumP[o * NSLOT + sl] = s;   // q <= 56*4*1152^2 = 2.97e8, fits int32
            sqP[o * NSLOT + sl]  = q;
        }
    }
}

// ---------------------------------------------------------------------------
// K4: fold partial stats + scale + BN + bias1 into per-channel affine.
// 128 blocks x 64 threads; each block reduces 448 partials for one channel.
// ---------------------------------------------------------------------------
__global__ __launch_bounds__(64) void bn_coef2(const int* __restrict__ sumP,
                                               const int* __restrict__ sqP,
                                               const float* __restrict__ scaleW,
                                               const float* __restrict__ gamma,
                                               const float* __restrict__ beta,
                                               const float* __restrict__ bias1,
                                               float* __restrict__ coefA,
                                               float* __restrict__ coefB) {
    int o = blockIdx.x;
    int t = threadIdx.x;
    long long s = 0, q = 0;
    for (int i = t; i < NSLOT; i += 64) {
        s += sumP[o * NSLOT + i];
        q += sqP[o * NSLOT + i];
    }
#pragma unroll
    for (int off = 32; off; off >>= 1) {
        s += __shfl_down(s, off);
        q += __shfl_down(q, off);
    }
    if (t == 0) {
        double cnt = (double)NPIX;
        double mean = (double)s / cnt;
        double var = (double)q / cnt - mean * mean;
        if (var < 0.0) var = 0.0;
        float sc = scaleW[o];
        float rs = rsqrtf((float)((double)sc * (double)sc * var) + 1e-5f);
        float g = gamma[o];
        coefA[o] = sc * g * rs;
        coefB[o] = beta[o] - (float)((double)sc * mean) * g * rs + bias1[o];
    }
}

// ---------------------------------------------------------------------------
// K5: elementwise epilogue, 8 elems/thread vectorized.
// out = prelu(coefA*y + coefB + x) + bias2
// ---------------------------------------------------------------------------
__global__ __launch_bounds__(256) void final_store(const short* __restrict__ yI,
                                                   const float* __restrict__ x,
                                                   const float* __restrict__ coefA,
                                                   const float* __restrict__ coefB,
                                                   const float* __restrict__ alpha,
                                                   const float* __restrict__ bias2,
                                                   float* __restrict__ out) {
    const size_t ngroups = (size_t)NB * NO * NHW_ / 8;
    for (size_t g = (size_t)blockIdx.x * blockDim.x + threadIdx.x; g < ngroups;
         g += (size_t)gridDim.x * blockDim.x) {
        size_t i = g * 8;
        int o = (int)((i / NHW_) % NO);
        float a = coefA[o], bb = coefB[o], al = alpha[o], b2 = bias2[o];
        int4 yv = *reinterpret_cast<const int4*>(yI + i);
        float4 x0 = *reinterpret_cast<const float4*>(x + i);
        float4 x1 = *reinterpret_cast<const float4*>(x + i + 4);
        int q[4] = {yv.x, yv.y, yv.z, yv.w};
        float xs[8] = {x0.x, x0.y, x0.z, x0.w, x1.x, x1.y, x1.z, x1.w};
        float r[8];
#pragma unroll
        for (int j = 0; j < 4; ++j) {
            float lo = (float)(short)(q[j] & 0xffff);
            float hi = (float)(q[j] >> 16);
            float t0 = fmaf(a, lo, bb) + xs[2 * j];
            float t1 = fmaf(a, hi, bb) + xs[2 * j + 1];
            t0 = t0 >= 0.f ? t0 : al * t0;
            t1 = t1 >= 0.f ? t1 : al * t1;
            r[2 * j]     = t0 + b2;
            r[2 * j + 1] = t1 + b2;
        }
        float4 o0 = {r[0], r[1], r[2], r[3]};
        float4 o1 = {r[4], r[5], r[6], r[7]};
        *reinterpret_cast<float4*>(out + i)     = o0;
        *reinterpret_cast<float4*>(out + i + 4) = o1;
    }
}

// ---------------------------------------------------------------------------
// Fallback path (tiny-ws): atomic-based stats conv + recompute epilogue.
// ---------------------------------------------------------------------------
__device__ inline void load_nbhd(const u64* __restrict__ packA, int n, int h,
                                 int wcol, bool act, u64 a[9][2], unsigned* vmask) {
    unsigned m = 0;
#pragma unroll
    for (int kh = 0; kh < 3; ++kh) {
        int hi = h + kh - 1;
        bool vh = (hi >= 0) && (hi < NH);
#pragma unroll
        for (int kw = 0; kw < 3; ++kw) {
            int wi = wcol + kw - 1;
            int t = kh * 3 + kw;
            bool v = act && vh && (wi >= 0) && (wi < NW);
            int hc = hi < 0 ? 0 : (hi >= NH ? NH - 1 : hi);
            int wc = wi < 0 ? 0 : (wi >= NW ? NW - 1 : wi);
            size_t idx = ((size_t)n * NHW_ + (size_t)hc * NW + wc) * 2;
            u64 q0 = packA[idx], q1 = packA[idx + 1];
            a[t][0] = v ? q0 : 0;
            a[t][1] = v ? q1 : 0;
            m |= (unsigned)v << t;
        }
    }
    *vmask = m;
}

__global__ __launch_bounds__(256) void conv_stats_atomic(const u64* __restrict__ packA,
                                                         const u64* __restrict__ packW,
                                                         int* __restrict__ sumI,
                                                         u64* __restrict__ sumsqI) {
    __shared__ u64 lw[NO * 18];
    for (int i = threadIdx.x; i < NO * 18; i += 256) lw[i] = packW[i];
    int nh = blockIdx.x;
    int n = nh / NH, h = nh - n * NH;
    int wave = threadIdx.x >> 6, lane = threadIdx.x & 63;
    bool act = lane < NW;
    u64 a[9][2]; unsigned vm;
    load_nbhd(packA, n, h, lane, act, a, &vm);
    __syncthreads();
    for (int oo = 0; oo < 32; ++oo) {
        int o = (wave << 5) + oo;
        int dot = 0;
#pragma unroll
        for (int t = 0; t < 9; ++t) {
            int pc = __popcll(a[t][0] ^ lw[(o * 9 + t) * 2]) +
                     __popcll(a[t][1] ^ lw[(o * 9 + t) * 2 + 1]);
            dot += ((vm >> t) & 1) ? (NC - 2 * pc) : 0;
        }
        int s = dot, sq = dot * dot;
        for (int off = 32; off; off >>= 1) {
            s  += __shfl_down(s, off);
            sq += __shfl_down(sq, off);
        }
        if (lane == 0) {
            atomicAdd(&sumI[o], s);
            atomicAdd(&sumsqI[o], (u64)(unsigned)sq);
        }
    }
}

__global__ __launch_bounds__(128) void bn_coef(const int* __restrict__ sumP,
                                               const u64* __restrict__ sqP,
                                               const float* __restrict__ scaleW,
                                               const float* __restrict__ gamma,
                                               const float* __restrict__ beta,
                                               const float* __restrict__ bias1,
                                               float* __restrict__ coefA,
                                               float* __restrict__ coefB) {
    int o = threadIdx.x;
    double cnt = (double)NPIX;
    double mean = (double)sumP[o] / cnt;
    double var = (double)sqP[o] / cnt - mean * mean;
    if (var < 0.0) var = 0.0;
    float sc = scaleW[o];
    float rs = rsqrtf((float)((double)sc * (double)sc * var) + 1e-5f);
    float g = gamma[o];
    coefA[o] = sc * g * rs;
    coefB[o] = beta[o] - (float)((double)sc * mean) * g * rs + bias1[o];
}

__global__ __launch_bounds__(256) void final_recompute(const u64* __restrict__ packA,
                                                       const u64* __restrict__ packW,
                                                       const float* __restrict__ coefA,
                                                       const float* __restrict__ coefB,
                                                       const float* __restrict__ alpha,
                                                       const float* __restrict__ bias2,
                                                       const float* __restrict__ x,
                                                       float* __restrict__ out) {
    __shared__ u64 lw[NO * 18];
    for (int i = threadIdx.x; i < NO * 18; i += 256) lw[i] = packW[i];
    int nh = blockIdx.x;
    int n = nh / NH, h = nh - n * NH;
    int wave = threadIdx.x >> 6, lane = threadIdx.x & 63;
    bool act = lane < NW;
    u64 a[9][2]; unsigned vm;
    load_nbhd(packA, n, h, lane, act, a, &vm);
    __syncthreads();
    for (int oo = 0; oo < 32; ++oo) {
        int o = (wave << 5) + oo;
        int dot = 0;
#pragma unroll
        for (int t = 0; t < 9; ++t) {
            int pc = __popcll(a[t][0] ^ lw[(o * 9 + t) * 2]) +
                     __popcll(a[t][1] ^ lw[(o * 9 + t) * 2 + 1]);
            dot += ((vm >> t) & 1) ? (NC - 2 * pc) : 0;
        }
        if (act) {
            size_t idx = ((size_t)n * NO + o) * NHW_ + (size_t)h * NW + lane;
            float t = fmaf(coefA[o], (float)dot, coefB[o]) + x[idx];
            t = t >= 0.f ? t : alpha[o] * t;
            out[idx] = t + bias2[o];
        }
    }
}

// ---------------------------------------------------------------------------
// Workspace layout (bytes):
//   0        packA   (NB*HW*2 u64)      1,605,632
//   1605632  packW   (128*18 u64)          18,432
//   1624064  corrW   (128*8 i32)            4,096
//   1628160  scaleW  (128 f32)                512
//   1628672  coefA   (128 f32)                512
//   1629184  coefB   (128 f32)                512
//   1629696  sumI    (128 i32, fallback)      512
//   1630208  sqI     (128 u64, fallback)    1,024
//   1631232  sumP    (128*448 i32)        229,376
//   1860608  sqP     (128*448 i32)        229,376
//   2089984  yI      (int16)           25,690,112   -> total 27,780,096
// ---------------------------------------------------------------------------
extern "C" void kernel_launch(void* const* d_in, const int* in_sizes, int n_in,
                              void* d_out, int out_size, void* d_ws, size_t ws_size,
                              hipStream_t stream) {
    (void)in_sizes; (void)n_in; (void)out_size;
    const float* x     = (const float*)d_in[0];
    const float* bias0 = (const float*)d_in[1];
    const float* w     = (const float*)d_in[2];
    const float* gamma = (const float*)d_in[3];
    const float* beta  = (const float*)d_in[4];
    const float* bias1 = (const float*)d_in[5];
    const float* alpha = (const float*)d_in[6];
    const float* bias2 = (const float*)d_in[7];
    float* out = (float*)d_out;
    char* ws = (char*)d_ws;

    u64*   packA  = (u64*)ws;
    u64*   packW  = (u64*)(ws + 1605632);
    int*   corrW  = (int*)(ws + 1624064);
    float* scaleW = (float*)(ws + 1628160);
    float* coefA  = (float*)(ws + 1628672);
    float* coefB  = (float*)(ws + 1629184);
    int*   sumI   = (int*)(ws + 1629696);
    u64*   sqI    = (u64*)(ws + 1630208);
    int*   sumP   = (int*)(ws + 1631232);
    int*   sqP    = (int*)(ws + 1860608);
    short* yI     = (short*)(ws + 2089984);
    bool store = ws_size >= (size_t)2089984 + (size_t)NB * NO * NHW_ * 2;

    pack_act<<<NPIX / 256, 256, 0, stream>>>(x, bias0, packA);
    pack_wgt<<<NO, 64, 0, stream>>>(w, packW, scaleW, corrW);

    if (store) {
        conv_bin<<<NB * NSTRIP * 4, 256, 0, stream>>>(packA, packW, corrW, yI, sumP, sqP);
        bn_coef2<<<NO, 64, 0, stream>>>(sumP, sqP, scaleW, gamma, beta, bias1, coefA, coefB);
        final_store<<<2048, 256, 0, stream>>>(yI, x, coefA, coefB, alpha, bias2, out);
    } else {
        hipMemsetAsync(sumI, 0, 512 + 1024, stream);
        conv_stats_atomic<<<NB * NH, 256, 0, stream>>>(packA, packW, sumI, sqI);
        bn_coef<<<1, NO, 0, stream>>>(sumI, sqI, scaleW, gamma, beta, bias1, coefA, coefB);
        final_recompute<<<NB * NH, 256, 0, stream>>>(packA, packW, coefA, coefB, alpha, bias2, x, out);
    }
}